// Round 10
// baseline (310.378 us; speedup 1.0000x reference)
//
#include <hip/hip_runtime.h>

typedef unsigned short u16;
typedef unsigned int   u32;
typedef __bf16 bf16x8 __attribute__((ext_vector_type(8)));
typedef float  f32x4  __attribute__((ext_vector_type(4)));

#define DEVI __device__ __forceinline__

DEVI u16 f2bf(float f) {
    union { float f; u32 u; } c; c.f = f;
    u32 u = c.u;
    u32 r = (u + 0x7fffu + ((u >> 16) & 1u)) >> 16;
    return (u16)r;
}
DEVI float bf2f(u16 v) {
    union { u32 u; float f; } c; c.u = ((u32)v) << 16;
    return c.f;
}

DEVI void gload16(const void* g, void* l) {
    __builtin_amdgcn_global_load_lds(
        (const __attribute__((address_space(1))) void*)g,
        (__attribute__((address_space(3))) void*)l, 16, 0, 0);
}

// ------------- 256x256 GEMM, A register-direct, B LDS-staged -------------
// A-frags load straight from global (L2) into VGPRs, one tile ahead
// (ping-pong aA/aB; 6-tile unrolled body keeps buffer %3 / array %2 static).
// B staged via global_load_lds into 3 x 16KB buffers ([256 rows][32 K],
// chunk swizzle: physical 16B chunk p holds logical p^(row&3)).
// ONE raw barrier per K-tile, no asm waitcnt in the loop: the compiler's
// counted vmcnt for the aCur register dependency (issued AFTER the previous
// B-stage; vmcnt completes in order) transitively drains B(t+1) before each
// wave's MFMA burst, and the closing barrier globalizes it. Prologue does
// one explicit full drain.

#define VMW0    asm volatile("s_waitcnt vmcnt(0)" ::: "memory")
#define BAR     __builtin_amdgcn_s_barrier()
#define SP1     __builtin_amdgcn_s_setprio(1)
#define SP0     __builtin_amdgcn_s_setprio(0)

// stage one 16KB B slot (256 rows x 32 cols bf16): 2 x 16B per thread
DEVI void stage_kh(const u16* g, u16* slot, int tid) {
    const int wvb = (tid >> 6) << 9;             // wave base (u16), dest linear
    const int r = tid >> 2;                      // row 0..127 (and +128)
    const int p = tid & 3;
    const int c = p ^ (r & 3);                   // pre-swizzled source chunk
    const long off = (long)r * 1024 + (c << 3);
    gload16(g + off, slot + wvb);
    gload16(g + off + (long)128 * 1024, slot + 4096 + wvb);
}

DEVI f32x4 mfma(const bf16x8& a, const bf16x8& b, const f32x4& c) {
    return __builtin_amdgcn_mfma_f32_16x16x32_bf16(a, b, c, 0, 0, 0);
}

// one K-tile: optional stage B(TSTG)->QSTG, optional A(TNXT)->ANXT,
// read B-frags from QCUR, 32 MFMA on ACUR, barrier.
#define GT(QCUR, QSTG, ACUR, ANXT, TSTG, TNXT, DO_STAGE, DO_LOAD, DO_BAR)   \
    {                                                                        \
        if (DO_STAGE) stage_kh(Bb + (TSTG) * 32, lds + (QSTG), tid);         \
        if (DO_LOAD) {                                                       \
            _Pragma("unroll")                                                \
            for (int m = 0; m < 8; ++m)                                      \
                ANXT[m] = *(const bf16x8*)(Aq + (TNXT) * 32 + m * 16384);    \
        }                                                                    \
        _Pragma("unroll")                                                    \
        for (int nf = 0; nf < 4; ++nf)                                       \
            bh[nf] = *(const bf16x8*)(lds + (QCUR) + bbase + nf * 512);      \
        SP1;                                                                 \
        _Pragma("unroll")                                                    \
        for (int m = 0; m < 8; ++m) {                                        \
            _Pragma("unroll")                                                \
            for (int nf = 0; nf < 4; ++nf)                                   \
                acc[m][nf] = mfma(ACUR[m], bh[nf], acc[m][nf]);              \
        }                                                                    \
        SP0;                                                                 \
        if (DO_BAR) BAR;                                                     \
    }

DEVI void pipe256(const u16* Ab, const u16* Bb, u16* lds,
                  f32x4 (&acc)[8][4], int tid) {
    const int lane = tid & 63;
    const int wm = (tid >> 6) >> 2, wn = (tid >> 6) & 3;
    const int pch = ((lane >> 4) ^ (lane & 3)) << 3;
    const int bbase = (wn * 64 + (lane & 15)) * 32 + pch;     // B slot-rel
    // per-lane A base: row = wm*128 + (lane&15), k-chunk = (lane>>4)*8
    const u16* Aq = Ab + (long)(wm * 128 + (lane & 15)) * 1024 + ((lane >> 4) << 3);

    bf16x8 aA[8], aB[8], bh[4];

    // prologue: B(t0)->buf0, B(t1)->buf1; A(t0)->aA; full drain once.
    stage_kh(Bb,      lds + 0,    tid);
    stage_kh(Bb + 32, lds + 8192, tid);
#pragma unroll
    for (int m = 0; m < 8; ++m)
        aA[m] = *(const bf16x8*)(Aq + m * 16384);
    VMW0; BAR;

#pragma unroll 1
    for (int j = 0; j < 5; ++j) {
        const int t = j * 6;
        GT(0,     16384, aA, aB, t + 2, t + 1, 1, 1, 1);   // tile t
        GT(8192,  0,     aB, aA, t + 3, t + 2, 1, 1, 1);   // t+1
        GT(16384, 8192,  aA, aB, t + 4, t + 3, 1, 1, 1);   // t+2
        GT(0,     16384, aB, aA, t + 5, t + 4, 1, 1, 1);   // t+3
        GT(8192,  0,     aA, aB, t + 6, t + 5, 1, 1, 1);   // t+4
        GT(16384, 8192,  aB, aA, t + 7, t + 6, 1, 1, 1);   // t+5
    }
    // tail: tile 30 (buf0, aA; load A31), tile 31 (buf1, aB)
    GT(0,    0, aA, aB, 0, 31, 0, 1, 1);
    GT(8192, 0, aB, aA, 0, 0,  0, 0, 0);
}

// ---------------- gate GEMM: P = A @ Bcat^T, fused sigmoid-gate epilogue ----
// writes packed ab[row*1024 + ch] = bf16(a) | bf16(b)<<16

__global__ __launch_bounds__(512, 2) void k_gemm_cat8(
    const u16* __restrict__ A, const u16* __restrict__ Bcat,
    const float* __restrict__ gb, const float* __restrict__ ib,
    u32* __restrict__ ab) {
    __shared__ __align__(16) u16 lds[24576];      // 48KB: 3 B-buffers
    const int tid = threadIdx.x, lane = tid & 63;
    const int wm = (tid >> 6) >> 2, wn = (tid >> 6) & 3;

    // bijective XCD swizzle, grid (8, 64) = 512 wg
    int fid = (int)blockIdx.y * 8 + (int)blockIdx.x;
    int swz = (fid & 7) * 64 + (fid >> 3);
    const long bn = swz & 7, bm = swz >> 3;

    f32x4 acc[8][4] = {};
    pipe256(A + bm * 256 * 1024, Bcat + bn * 256 * 1024, lds, acc, tid);

    const long rbase = bm * 256 + wm * 128;
    const int chbase = (int)bn * 128 + wn * 32;
#pragma unroll
    for (int t = 0; t < 2; ++t) {
        int ch = chbase + t * 16 + (lane & 15);
        float g0 = gb[ch], i0 = ib[ch];
#pragma unroll
        for (int m = 0; m < 8; ++m) {
            long row = rbase + m * 16 + ((lane >> 4) << 2);
#pragma unroll
            for (int i = 0; i < 4; ++i) {
                float pg = acc[m][2 * t][i] + g0;
                float pi = acc[m][2 * t + 1][i] + i0;
                float aa = 1.0f / (1.0f + __expf(-pg));
                float bb = (1.0f - aa) * pi;
                ab[(row + i) * 1024 + ch] = (u32)f2bf(aa) | ((u32)f2bf(bb) << 16);
            }
        }
    }
}

// ---------------- final GEMM: out = h @ out_w + x + out_b ----------------

__global__ __launch_bounds__(512, 2) void k_gemm_out8(
    const u16* __restrict__ A, const u16* __restrict__ Bt,
    const float* __restrict__ xres, const float* __restrict__ ob,
    float* __restrict__ out) {
    __shared__ __align__(16) u16 lds[24576];
    const int tid = threadIdx.x, lane = tid & 63;
    const int wm = (tid >> 6) >> 2, wn = (tid >> 6) & 3;

    // bijective XCD swizzle, grid (4, 64) = 256 wg
    int fid = (int)blockIdx.y * 4 + (int)blockIdx.x;
    int swz = (fid & 7) * 32 + (fid >> 3);
    const long bn = swz & 3, bm = swz >> 2;

    f32x4 acc[8][4] = {};
    pipe256(A + bm * 256 * 1024, Bt + bn * 256 * 1024, lds, acc, tid);

    const long rbase = bm * 256 + wm * 128;
    const int cbase = (int)bn * 256 + wn * 64;
#pragma unroll
    for (int n = 0; n < 4; ++n) {
        int col = cbase + n * 16 + (lane & 15);
        float o0 = ob[col];
#pragma unroll
        for (int m = 0; m < 8; ++m) {
            long row = rbase + m * 16 + ((lane >> 4) << 2);
#pragma unroll
            for (int i = 0; i < 4; ++i) {
                long o = (row + i) * 1024 + col;
                out[o] = acc[m][n][i] + o0 + xres[o];
            }
        }
    }
}

// ---------------- conversions ----------------

__global__ __launch_bounds__(256) void k_cvt_x(const float4* __restrict__ x,
                                               uint2* __restrict__ o, int n4) {
    int i = blockIdx.x * 256 + threadIdx.x;
    if (i < n4) {
        float4 v = x[i];
        uint2 r;
        r.x = (u32)f2bf(v.x) | ((u32)f2bf(v.y) << 16);
        r.y = (u32)f2bf(v.z) | ((u32)f2bf(v.w) << 16);
        o[i] = r;
    }
}

__global__ __launch_bounds__(256) void k_transpose_bf(const float* __restrict__ w,
                                                      u16* __restrict__ wt, int R, int C) {
    __shared__ float t[32][33];
    int c0 = blockIdx.x * 32, r0 = blockIdx.y * 32;
    int x = threadIdx.x & 31, y = threadIdx.x >> 5;
    for (int i = y; i < 32; i += 8) t[i][x] = w[(size_t)(r0 + i) * C + c0 + x];
    __syncthreads();
    for (int i = y; i < 32; i += 8) wt[(size_t)(c0 + i) * R + r0 + x] = f2bf(t[x][i]);
}

// Interleaved concat transpose: rows 32t..32t+15 = gate ch 16t..16t+15,
// rows 32t+16..32t+31 = inp, same channels.
__global__ __launch_bounds__(256) void k_transpose_cat(const float* __restrict__ gw,
                                                       const float* __restrict__ iw,
                                                       u16* __restrict__ wt, int K, int C) {
    __shared__ float t[32][33];
    int c0 = blockIdx.x * 32, r0 = blockIdx.y * 32;
    const float* w = blockIdx.z ? iw : gw;
    int x = threadIdx.x & 31, y = threadIdx.x >> 5;
    for (int i = y; i < 32; i += 8) t[i][x] = w[(size_t)(r0 + i) * C + c0 + x];
    __syncthreads();
    for (int i = y; i < 32; i += 8) {
        int ch = c0 + i;
        int r = ((ch >> 4) << 5) | ((int)blockIdx.z << 4) | (ch & 15);
        wt[(size_t)r * K + r0 + x] = f2bf(t[x][i]);
    }
}

// ---------------- chunked affine scan (packed ab stream) ----------------
// ab[row*1024 + ch]: lo = a (bf16), hi = b (bf16). h_t = a*h + b over s.

__global__ __launch_bounds__(256) void k_scanA(const u32* __restrict__ ab,
                                               float2* __restrict__ cAB) {
    int e = blockIdx.x * 256 + threadIdx.x;  // 0..1023
    int c = blockIdx.y, bt = blockIdx.z;
    long base = ((long)bt * 4096 + c * 64) * 1024 + e;
    float Aa = 1.f, H = 0.f;
#pragma unroll 4
    for (int i = 0; i < 64; ++i) {
        u32 v = ab[base + (long)i * 1024];
        float a = bf2f((u16)v), b = bf2f((u16)(v >> 16));
        H = a * H + b;
        Aa *= a;
    }
    cAB[((long)bt * 64 + c) * 1024 + e] = make_float2(Aa, H);
}

__global__ __launch_bounds__(256) void k_scanB(const float2* __restrict__ cAB,
                                               float* __restrict__ hin) {
    int e = blockIdx.x * 256 + threadIdx.x;
    int bt = blockIdx.y;
    float H = 0.f;
#pragma unroll
    for (int c = 0; c < 64; ++c) {
        long s = ((long)bt * 64 + c) * 1024 + e;
        hin[s] = H;
        float2 v = cAB[s];
        H = v.x * H + v.y;
    }
}

__global__ __launch_bounds__(256) void k_scanC(const u32* __restrict__ ab,
                                               const float* __restrict__ hin,
                                               u16* __restrict__ hout) {
    int e = blockIdx.x * 256 + threadIdx.x;
    int c = blockIdx.y, bt = blockIdx.z;
    long base = ((long)bt * 4096 + c * 64) * 1024 + e;
    float H = hin[((long)bt * 64 + c) * 1024 + e];
#pragma unroll 4
    for (int i = 0; i < 64; ++i) {
        u32 v = ab[base + (long)i * 1024];
        H = bf2f((u16)v) * H + bf2f((u16)(v >> 16));
        hout[base + (long)i * 1024] = f2bf(H);
    }
}

// ---------------- launch ----------------

extern "C" void kernel_launch(void* const* d_in, const int* in_sizes, int n_in,
                              void* d_out, int out_size, void* d_ws, size_t ws_size,
                              hipStream_t stream) {
    const float* x      = (const float*)d_in[0];
    const float* gate_w = (const float*)d_in[1];
    const float* gate_b = (const float*)d_in[2];
    const float* inp_w  = (const float*)d_in[3];
    const float* inp_b  = (const float*)d_in[4];
    const float* out_w  = (const float*)d_in[5];
    const float* out_b  = (const float*)d_in[6];
    float* out = (float*)d_out;

    const int Bsz = 4, S = 4096, Din = 1024, Dst = 1024;
    const int M = Bsz * S;                 // 16384
    const long nx = (long)M * Din;         // 16777216

    // workspace layout (bytes)
    char* w = (char*)d_ws;
    u16* xb      = (u16*)(w);                // 33,554,432  x bf16
    u16* catW    = (u16*)(w + 33554432);     //  4,194,304  [gate;inp] interleaved ^T
    u16* owT     = (u16*)(w + 37748736);     //  2,097,152  out_w^T bf16
    u16* hbf     = (u16*)(w + 39845888);     // 33,554,432  scan_out bf16
    float2* cAB  = (float2*)(w + 73400320);  //  2,097,152  chunk (A,H) pairs
    float* hin   = (float*)(w + 75497472);   //  1,048,576  chunk incoming states
    // total 76,546,048 B

    // packed ab lives in d_out (67,108,864 B); overwritten by final GEMM.
    u32* ab = (u32*)d_out;

    // 1. conversions
    k_cvt_x<<<(int)(nx / 4 / 256), 256, 0, stream>>>((const float4*)x, (uint2*)xb, (int)(nx / 4));
    k_transpose_cat<<<dim3(Dst / 32, Din / 32, 2), 256, 0, stream>>>(gate_w, inp_w, catW, Din, Dst);
    k_transpose_bf<<<dim3(Din / 32, Dst / 32), 256, 0, stream>>>(out_w, owT, Dst, Din);

    // 2. fused concat GEMM -> packed ab
    k_gemm_cat8<<<dim3(8, M / 256), 512, 0, stream>>>(xb, catW, gate_b, inp_b, ab);

    // 3. chunked scan -> h (bf16)
    k_scanA<<<dim3(4, 64, Bsz), 256, 0, stream>>>(ab, cAB);
    k_scanB<<<dim3(4, Bsz), 256, 0, stream>>>(cAB, hin);
    k_scanC<<<dim3(4, 64, Bsz), 256, 0, stream>>>(ab, hin, hbf);

    // 4. final GEMM: out = h @ out_w + x + out_b
    k_gemm_out8<<<dim3(4, M / 256), 512, 0, stream>>>(hbf, owT, x, out_b, out);
}

// Round 11
// 191.341 us; speedup vs baseline: 1.6221x; 1.6221x over previous
//
#include <hip/hip_runtime.h>

typedef unsigned short u16;
typedef unsigned int   u32;
typedef __bf16 bf16x8 __attribute__((ext_vector_type(8)));
typedef float  f32x4  __attribute__((ext_vector_type(4)));

#define DEVI __device__ __forceinline__

DEVI u16 f2bf(float f) {
    union { float f; u32 u; } c; c.f = f;
    u32 u = c.u;
    u32 r = (u + 0x7fffu + ((u >> 16) & 1u)) >> 16;
    return (u16)r;
}
DEVI float bf2f(u16 v) {
    union { u32 u; float f; } c; c.u = ((u32)v) << 16;
    return c.f;
}

DEVI void gload16(const void* g, void* l) {
    __builtin_amdgcn_global_load_lds(
        (const __attribute__((address_space(1))) void*)g,
        (__attribute__((address_space(3))) void*)l, 16, 0, 0);
}

// ---------- 128x128 m97-shape GEMM: 256 threads, 3 blocks/CU ----------
// Small block (acc[4][4] = 64 AGPR, ~70 VGPR) -> ~12 waves/CU -> 3 blocks
// co-resident; cross-block overlap hides the stage-drain (m114), which the
// 8-wave/1-block variants (r4-r9, all 83-88us) could not.
// Buffer (16KB): A slot [128][32] @+0, B slot [128][32] @+4096 (u16), x3
// tri-buffer. Chunk swizzle: physical 16B chunk p holds logical p^(row&3);
// read chunk (lane>>4)^(lane&3). Stage t+2 during tile t; close = VMW(4)
// (t+1's 4 landed, t+2's 4 in flight; vmcnt per-wave, barrier globalizes).

#define VMW(N)  asm volatile("s_waitcnt vmcnt(" #N ")" ::: "memory")
#define BAR     __builtin_amdgcn_s_barrier()
#define SP1     __builtin_amdgcn_s_setprio(1)
#define SP0     __builtin_amdgcn_s_setprio(0)

// stage one 8KB slot (128 rows x 32 cols bf16) with 256 threads: 2x16B each
DEVI void stage128(const u16* g, u16* slot, int tid) {
    const int r = tid >> 2;                      // row 0..63 (and +64)
    const int p = tid & 3;
    const int c = p ^ (r & 3);                   // pre-swizzled source chunk
    const long off = (long)r * 1024 + (c << 3);
    gload16(g + off, slot + tid * 8);                    // rows 0..63
    gload16(g + off + 64 * 1024, slot + 2048 + tid * 8); // rows 64..127
}

DEVI f32x4 mfma(const bf16x8& a, const bf16x8& b, const f32x4& c) {
    return __builtin_amdgcn_mfma_f32_16x16x32_bf16(a, b, c, 0, 0, 0);
}

// one K-tile from buffer base Q: read 8 frags, 16 MFMA
#define TILE128(Q)                                                           \
    {                                                                        \
        _Pragma("unroll")                                                    \
        for (int m = 0; m < 4; ++m)                                          \
            af[m] = *(const bf16x8*)(lds + (Q) + aoff + m * 512);            \
        _Pragma("unroll")                                                    \
        for (int nf = 0; nf < 4; ++nf)                                       \
            bf[nf] = *(const bf16x8*)(lds + (Q) + boff + nf * 512);          \
        SP1;                                                                 \
        _Pragma("unroll")                                                    \
        for (int m = 0; m < 4; ++m) {                                        \
            _Pragma("unroll")                                                \
            for (int nf = 0; nf < 4; ++nf)                                   \
                acc[m][nf] = mfma(af[m], bf[nf], acc[m][nf]);                \
        }                                                                    \
        SP0;                                                                 \
    }

// full K=1024: 32 tiles, tri-buffer rotation (3-tile unrolled, 30 + 2 peel)
DEVI void pipe128(const u16* Ab, const u16* Bb, u16* lds,
                  f32x4 (&acc)[4][4], int tid) {
    const int lane = tid & 63;
    const int wm = (tid >> 6) >> 1, wn = (tid >> 6) & 1;
    const int pch = ((lane >> 4) ^ (lane & 3)) << 3;
    const int aoff = (wm * 64 + (lane & 15)) * 32 + pch;
    const int boff = 4096 + (wn * 64 + (lane & 15)) * 32 + pch;

    // prologue: t0 -> buf0, t1 -> buf1
    stage128(Ab,      lds + 0,     tid);
    stage128(Bb,      lds + 4096,  tid);
    stage128(Ab + 32, lds + 8192,  tid);
    stage128(Bb + 32, lds + 12288, tid);
    VMW(4); BAR;                          // t0 landed; t1 in flight

    bf16x8 af[4], bf[4];

#pragma unroll 1
    for (int j = 0; j < 10; ++j) {
        const int t = j * 3;
        // tile t (buf0): stage t+2 -> buf2
        stage128(Ab + (t + 2) * 32, lds + 16384, tid);
        stage128(Bb + (t + 2) * 32, lds + 20480, tid);
        TILE128(0);
        VMW(4); BAR;
        // tile t+1 (buf1): stage t+3 -> buf0
        stage128(Ab + (t + 3) * 32, lds + 0,    tid);
        stage128(Bb + (t + 3) * 32, lds + 4096, tid);
        TILE128(8192);
        VMW(4); BAR;
        // tile t+2 (buf2): stage t+4 -> buf1
        stage128(Ab + (t + 4) * 32, lds + 8192,  tid);
        stage128(Bb + (t + 4) * 32, lds + 12288, tid);
        TILE128(16384);
        VMW(4); BAR;
    }
    // t=30 (buf0): no stage; t31's 4 outstanding -> drain
    TILE128(0);
    VMW(0); BAR;
    // t=31 (buf1)
    TILE128(8192);
}

// ---------------- gate GEMM: P = A @ Bcat^T, fused sigmoid-gate epilogue ----
// writes packed ab[row*1024 + ch] = bf16(a) | bf16(b)<<16

__global__ __launch_bounds__(256, 3) void k_gemm_cat8(
    const u16* __restrict__ A, const u16* __restrict__ Bcat,
    const float* __restrict__ gb, const float* __restrict__ ib,
    u32* __restrict__ ab) {
    __shared__ __align__(16) u16 lds[24576];     // 48KB tri-buffer
    const int tid = threadIdx.x, lane = tid & 63;
    const int wm = (tid >> 6) >> 1, wn = (tid >> 6) & 1;

    // bijective XCD swizzle, grid (16, 128) = 2048 wg
    int fid = (int)blockIdx.y * 16 + (int)blockIdx.x;
    int swz = (fid & 7) * 256 + (fid >> 3);
    const long bn = swz & 15, bm = swz >> 4;

    f32x4 acc[4][4] = {};
    pipe128(A + bm * 128 * 1024, Bcat + bn * 128 * 1024, lds, acc, tid);

    const long rbase = bm * 128 + wm * 64;
    const int chbase = (int)bn * 64 + wn * 32;
#pragma unroll
    for (int t = 0; t < 2; ++t) {
        int ch = chbase + t * 16 + (lane & 15);
        float g0 = gb[ch], i0 = ib[ch];
#pragma unroll
        for (int m = 0; m < 4; ++m) {
            long row = rbase + m * 16 + ((lane >> 4) << 2);
#pragma unroll
            for (int i = 0; i < 4; ++i) {
                float pg = acc[m][2 * t][i] + g0;
                float pi = acc[m][2 * t + 1][i] + i0;
                float aa = 1.0f / (1.0f + __expf(-pg));
                float bb = (1.0f - aa) * pi;
                ab[(row + i) * 1024 + ch] = (u32)f2bf(aa) | ((u32)f2bf(bb) << 16);
            }
        }
    }
}

// -------- final GEMM: out = h @ out_w + x + out_b (x residual as bf16) ------

__global__ __launch_bounds__(256, 3) void k_gemm_out8(
    const u16* __restrict__ A, const u16* __restrict__ Bt,
    const u16* __restrict__ xbf, const float* __restrict__ ob,
    float* __restrict__ out) {
    __shared__ __align__(16) u16 lds[24576];
    const int tid = threadIdx.x, lane = tid & 63;
    const int wm = (tid >> 6) >> 1, wn = (tid >> 6) & 1;

    // bijective XCD swizzle, grid (8, 128) = 1024 wg
    int fid = (int)blockIdx.y * 8 + (int)blockIdx.x;
    int swz = (fid & 7) * 128 + (fid >> 3);
    const long bn = swz & 7, bm = swz >> 3;

    f32x4 acc[4][4] = {};
    pipe128(A + bm * 128 * 1024, Bt + bn * 128 * 1024, lds, acc, tid);

    const long rbase = bm * 128 + wm * 64;
    const int cbase = (int)bn * 128 + wn * 64;
#pragma unroll
    for (int n = 0; n < 4; ++n) {
        int col = cbase + n * 16 + (lane & 15);
        float o0 = ob[col];
#pragma unroll
        for (int m = 0; m < 4; ++m) {
            long row = rbase + m * 16 + ((lane >> 4) << 2);
#pragma unroll
            for (int i = 0; i < 4; ++i) {
                long o = (row + i) * 1024 + col;
                out[o] = acc[m][n][i] + o0 + bf2f(xbf[o]);
            }
        }
    }
}

// ---------------- conversions ----------------

__global__ __launch_bounds__(256) void k_cvt_x(const float4* __restrict__ x,
                                               uint2* __restrict__ o, int n4) {
    int i = blockIdx.x * 256 + threadIdx.x;
    if (i < n4) {
        float4 v = x[i];
        uint2 r;
        r.x = (u32)f2bf(v.x) | ((u32)f2bf(v.y) << 16);
        r.y = (u32)f2bf(v.z) | ((u32)f2bf(v.w) << 16);
        o[i] = r;
    }
}

__global__ __launch_bounds__(256) void k_transpose_bf(const float* __restrict__ w,
                                                      u16* __restrict__ wt, int R, int C) {
    __shared__ float t[32][33];
    int c0 = blockIdx.x * 32, r0 = blockIdx.y * 32;
    int x = threadIdx.x & 31, y = threadIdx.x >> 5;
    for (int i = y; i < 32; i += 8) t[i][x] = w[(size_t)(r0 + i) * C + c0 + x];
    __syncthreads();
    for (int i = y; i < 32; i += 8) wt[(size_t)(c0 + i) * R + r0 + x] = f2bf(t[x][i]);
}

// Interleaved concat transpose: rows 32t..32t+15 = gate ch 16t..16t+15,
// rows 32t+16..32t+31 = inp, same channels.
__global__ __launch_bounds__(256) void k_transpose_cat(const float* __restrict__ gw,
                                                       const float* __restrict__ iw,
                                                       u16* __restrict__ wt, int K, int C) {
    __shared__ float t[32][33];
    int c0 = blockIdx.x * 32, r0 = blockIdx.y * 32;
    const float* w = blockIdx.z ? iw : gw;
    int x = threadIdx.x & 31, y = threadIdx.x >> 5;
    for (int i = y; i < 32; i += 8) t[i][x] = w[(size_t)(r0 + i) * C + c0 + x];
    __syncthreads();
    for (int i = y; i < 32; i += 8) {
        int ch = c0 + i;
        int r = ((ch >> 4) << 5) | ((int)blockIdx.z << 4) | (ch & 15);
        wt[(size_t)r * K + r0 + x] = f2bf(t[x][i]);
    }
}

// ---------------- chunked affine scan (packed ab stream) ----------------
// ab[row*1024 + ch]: lo = a (bf16), hi = b (bf16). h_t = a*h + b over s.

__global__ __launch_bounds__(256) void k_scanA(const u32* __restrict__ ab,
                                               float2* __restrict__ cAB) {
    int e = blockIdx.x * 256 + threadIdx.x;  // 0..1023
    int c = blockIdx.y, bt = blockIdx.z;
    long base = ((long)bt * 4096 + c * 64) * 1024 + e;
    float Aa = 1.f, H = 0.f;
#pragma unroll 4
    for (int i = 0; i < 64; ++i) {
        u32 v = ab[base + (long)i * 1024];
        float a = bf2f((u16)v), b = bf2f((u16)(v >> 16));
        H = a * H + b;
        Aa *= a;
    }
    cAB[((long)bt * 64 + c) * 1024 + e] = make_float2(Aa, H);
}

__global__ __launch_bounds__(256) void k_scanB(const float2* __restrict__ cAB,
                                               float* __restrict__ hin) {
    int e = blockIdx.x * 256 + threadIdx.x;
    int bt = blockIdx.y;
    float H = 0.f;
#pragma unroll
    for (int c = 0; c < 64; ++c) {
        long s = ((long)bt * 64 + c) * 1024 + e;
        hin[s] = H;
        float2 v = cAB[s];
        H = v.x * H + v.y;
    }
}

__global__ __launch_bounds__(256) void k_scanC(const u32* __restrict__ ab,
                                               const float* __restrict__ hin,
                                               u16* __restrict__ hout) {
    int e = blockIdx.x * 256 + threadIdx.x;
    int c = blockIdx.y, bt = blockIdx.z;
    long base = ((long)bt * 4096 + c * 64) * 1024 + e;
    float H = hin[((long)bt * 64 + c) * 1024 + e];
#pragma unroll 4
    for (int i = 0; i < 64; ++i) {
        u32 v = ab[base + (long)i * 1024];
        H = bf2f((u16)v) * H + bf2f((u16)(v >> 16));
        hout[base + (long)i * 1024] = f2bf(H);
    }
}

// ---------------- launch ----------------

extern "C" void kernel_launch(void* const* d_in, const int* in_sizes, int n_in,
                              void* d_out, int out_size, void* d_ws, size_t ws_size,
                              hipStream_t stream) {
    const float* x      = (const float*)d_in[0];
    const float* gate_w = (const float*)d_in[1];
    const float* gate_b = (const float*)d_in[2];
    const float* inp_w  = (const float*)d_in[3];
    const float* inp_b  = (const float*)d_in[4];
    const float* out_w  = (const float*)d_in[5];
    const float* out_b  = (const float*)d_in[6];
    float* out = (float*)d_out;

    const int Bsz = 4, S = 4096, Din = 1024, Dst = 1024;
    const int M = Bsz * S;                 // 16384
    const long nx = (long)M * Din;         // 16777216

    // workspace layout (bytes)
    char* w = (char*)d_ws;
    u16* xb      = (u16*)(w);                // 33,554,432  x bf16
    u16* catW    = (u16*)(w + 33554432);     //  4,194,304  [gate;inp] interleaved ^T
    u16* owT     = (u16*)(w + 37748736);     //  2,097,152  out_w^T bf16
    u16* hbf     = (u16*)(w + 39845888);     // 33,554,432  scan_out bf16
    float2* cAB  = (float2*)(w + 73400320);  //  2,097,152  chunk (A,H) pairs
    float* hin   = (float*)(w + 75497472);   //  1,048,576  chunk incoming states
    // total 76,546,048 B

    // packed ab lives in d_out (67,108,864 B); overwritten by final GEMM.
    u32* ab = (u32*)d_out;

    // 1. conversions
    k_cvt_x<<<(int)(nx / 4 / 256), 256, 0, stream>>>((const float4*)x, (uint2*)xb, (int)(nx / 4));
    k_transpose_cat<<<dim3(Dst / 32, Din / 32, 2), 256, 0, stream>>>(gate_w, inp_w, catW, Din, Dst);
    k_transpose_bf<<<dim3(Din / 32, Dst / 32), 256, 0, stream>>>(out_w, owT, Dst, Din);

    // 2. fused concat GEMM -> packed ab   (grid 16 x 128 = 2048 wg)
    k_gemm_cat8<<<dim3(16, M / 128), 256, 0, stream>>>(xb, catW, gate_b, inp_b, ab);

    // 3. chunked scan -> h (bf16)
    k_scanA<<<dim3(4, 64, Bsz), 256, 0, stream>>>(ab, cAB);
    k_scanB<<<dim3(4, Bsz), 256, 0, stream>>>(cAB, hin);
    k_scanC<<<dim3(4, 64, Bsz), 256, 0, stream>>>(ab, hin, hbf);

    // 4. final GEMM: out = h @ out_w + x + out_b   (grid 8 x 128 = 1024 wg)
    k_gemm_out8<<<dim3(8, M / 128), 256, 0, stream>>>(hbf, owT, xb, out_b, out);
}

// Round 12
// 190.465 us; speedup vs baseline: 1.6296x; 1.0046x over previous
//
#include <hip/hip_runtime.h>

typedef unsigned short u16;
typedef unsigned int   u32;
typedef __bf16 bf16x8 __attribute__((ext_vector_type(8)));
typedef float  f32x4  __attribute__((ext_vector_type(4)));

#define DEVI __device__ __forceinline__

DEVI u16 f2bf(float f) {
    union { float f; u32 u; } c; c.f = f;
    u32 u = c.u;
    u32 r = (u + 0x7fffu + ((u >> 16) & 1u)) >> 16;
    return (u16)r;
}
DEVI float bf2f(u16 v) {
    union { u32 u; float f; } c; c.u = ((u32)v) << 16;
    return c.f;
}

DEVI void gload16(const void* g, void* l) {
    __builtin_amdgcn_global_load_lds(
        (const __attribute__((address_space(1))) void*)g,
        (__attribute__((address_space(3))) void*)l, 16, 0, 0);
}

// ---------------- 256x256 m201-geometry 8-phase GEMM ----------------
// LDS 128KB: buffer q at q*32768 (u16). Halves (16KB, [128 rows][64 K] bf16,
// 128B row stride): A0 @+0, A1 @+8192, B0 @+16384, B1 @+24576.
// st_16x32 swizzle: byte ^= ((byte>>9)&1)<<5 within each half ->
//   u16 off(r,k) = r*64 + (k ^ (((r>>2)&1)<<4)).
// DMA dest stays LINEAR; the global SOURCE column is pre-swizzled with the
// same XOR (rule 21: source permutation == read permutation).
// Iter = 2 K-tiles x 4 phases. Phase: [ph1: 8 B-frags held in regs] +
// 4 A-reads; 1 half-tile stage; [lgkmcnt(8) if 12 reads]; BAR; lgkmcnt(0)+
// sched_barrier; setprio(1); 16 MFMA; setprio(0); [VMW(4) at ph4]; BAR.
// Ledger: stage T+1.A0/A1 at T.ph1/ph2, T+2.B0/B1 at T.ph3/ph4; gate VMW(4)
// at each tile's ph4 leaves exactly the last 2 halves in flight; every half
// is landed >= 1 gate before its consuming ph1 (vmcnt per-wave; the closing
// barrier globalizes). Prologue: 6 halves, VMW(4). Tail: VMW(0) at T14.ph4.

#define VMW(N)  asm volatile("s_waitcnt vmcnt(" #N ")" ::: "memory")
#define LGKM(N) asm volatile("s_waitcnt lgkmcnt(" #N ")" ::: "memory")
#define BAR     __builtin_amdgcn_s_barrier()
#define SP1     __builtin_amdgcn_s_setprio(1)
#define SP0     __builtin_amdgcn_s_setprio(0)
#define SCB     __builtin_amdgcn_sched_barrier(0)

// stage one 16KB half ([128][64] bf16) with 512 threads: 2 x 16B each.
// dest linear (tid*16B); source column pre-swizzled by ((r>>2)&1)<<5 bytes.
DEVI void stage_half(const u16* g, u16* slot, int tid) {
    const int r = tid >> 3;                                  // 0..63
    const int ks = ((tid & 7) << 3) ^ (((tid >> 5) & 1) << 4);
    gload16(g + (long)r * 1024 + ks, slot + tid * 8);
    gload16(g + (long)(r + 64) * 1024 + ks, slot + 4096 + tid * 8);
}

DEVI f32x4 mfma(const bf16x8& a, const bf16x8& b, const f32x4& c) {
    return __builtin_amdgcn_mfma_f32_16x16x32_bf16(a, b, c, 0, 0, 0);
}

// one phase: Q = buffer base, M2 = m-pair (0..3)
#define PH(Q, M2, READB, STG, GATE)                                          \
    {                                                                        \
        if (READB) {                                                         \
            _Pragma("unroll")                                                \
            for (int n = 0; n < 4; ++n) {                                    \
                bh[n][0] = *(const bf16x8*)(lds + (Q) + bbase + n * 1024);   \
                bh[n][1] = *(const bf16x8*)(lds + (Q) + bbase + n * 1024 + 32); \
            }                                                                \
        }                                                                    \
        a0k0 = *(const bf16x8*)(lds + (Q) + abase + (M2) * 2048);            \
        a0k1 = *(const bf16x8*)(lds + (Q) + abase + (M2) * 2048 + 32);       \
        a1k0 = *(const bf16x8*)(lds + (Q) + abase + (M2) * 2048 + 1024);     \
        a1k1 = *(const bf16x8*)(lds + (Q) + abase + (M2) * 2048 + 1056);     \
        STG;                                                                 \
        if (READB) { LGKM(8); }                                              \
        BAR;                                                                 \
        LGKM(0); SCB;                                                        \
        SP1;                                                                 \
        _Pragma("unroll")                                                    \
        for (int n = 0; n < 4; ++n) {                                        \
            acc[(M2) * 2][n]     = mfma(a0k0, bh[n][0], acc[(M2) * 2][n]);   \
            acc[(M2) * 2][n]     = mfma(a0k1, bh[n][1], acc[(M2) * 2][n]);   \
            acc[(M2) * 2 + 1][n] = mfma(a1k0, bh[n][0], acc[(M2) * 2 + 1][n]); \
            acc[(M2) * 2 + 1][n] = mfma(a1k1, bh[n][1], acc[(M2) * 2 + 1][n]); \
        }                                                                    \
        SP0;                                                                 \
        GATE;                                                                \
        BAR;                                                                 \
    }

#define NOP do {} while (0)
#define AH(t, h) (Ab + (long)(h) * 131072 + (t) * 64)
#define BH(t, h) (Bb + (long)(h) * 131072 + (t) * 64)

DEVI void pipe256(const u16* Ab, const u16* Bb, u16* lds,
                  f32x4 (&acc)[8][4], int tid) {
    const int lane = tid & 63;
    const int wm = (tid >> 6) >> 2, wn = (tid >> 6) & 3;
    const int kswz = ((lane >> 4) << 3) ^ (((lane >> 2) & 1) << 4);
    const int abase = wm * 8192 + (lane & 15) * 64 + kswz;
    const int bbase = 16384 + (wn >> 1) * 8192 + ((wn & 1) * 64 + (lane & 15)) * 64 + kswz;

    // prologue: T0 all 4 halves + T1.B0/B1 (12 loads); drain T0, keep T1.B.
    stage_half(AH(0, 0), lds + 0,             tid);
    stage_half(AH(0, 1), lds + 8192,          tid);
    stage_half(BH(0, 0), lds + 16384,         tid);
    stage_half(BH(0, 1), lds + 24576,         tid);
    stage_half(BH(1, 0), lds + 32768 + 16384, tid);
    stage_half(BH(1, 1), lds + 32768 + 24576, tid);
    VMW(4); BAR;

    bf16x8 bh[4][2];
    bf16x8 a0k0, a0k1, a1k0, a1k1;

#pragma unroll 1
    for (int j = 0; j < 7; ++j) {
        const int T = 2 * j;
        // tile T (buf0)
        PH(0, 0, 1, stage_half(AH(T + 1, 0), lds + 32768, tid), NOP);
        PH(0, 1, 0, stage_half(AH(T + 1, 1), lds + 32768 + 8192, tid), NOP);
        PH(0, 2, 0, stage_half(BH(T + 2, 0), lds + 16384, tid), NOP);
        PH(0, 3, 0, stage_half(BH(T + 2, 1), lds + 24576, tid), VMW(4));
        // tile T+1 (buf1)
        PH(32768, 0, 1, stage_half(AH(T + 2, 0), lds + 0, tid), NOP);
        PH(32768, 1, 0, stage_half(AH(T + 2, 1), lds + 8192, tid), NOP);
        PH(32768, 2, 0, stage_half(BH(T + 3, 0), lds + 32768 + 16384, tid), NOP);
        PH(32768, 3, 0, stage_half(BH(T + 3, 1), lds + 32768 + 24576, tid), VMW(4));
    }
    // tail: tile 14 (stages T15.A only, full drain), tile 15 (no stages)
    PH(0, 0, 1, stage_half(AH(15, 0), lds + 32768, tid), NOP);
    PH(0, 1, 0, stage_half(AH(15, 1), lds + 32768 + 8192, tid), NOP);
    PH(0, 2, 0, NOP, NOP);
    PH(0, 3, 0, NOP, VMW(0));
    PH(32768, 0, 1, NOP, NOP);
    PH(32768, 1, 0, NOP, NOP);
    PH(32768, 2, 0, NOP, NOP);
    PH(32768, 3, 0, NOP, NOP);
}

// ---------------- gate GEMM: P = A @ Bcat^T, fused sigmoid-gate epilogue ----
// writes packed ab[row*1024 + ch] = bf16(a) | bf16(b)<<16

__global__ __launch_bounds__(512, 1) void k_gemm_cat8(
    const u16* __restrict__ A, const u16* __restrict__ Bcat,
    const float* __restrict__ gb, const float* __restrict__ ib,
    u32* __restrict__ ab) {
    __shared__ __align__(16) u16 lds[65536];
    const int tid = threadIdx.x, lane = tid & 63;
    const int wm = (tid >> 6) >> 2, wn = (tid >> 6) & 3;

    // bijective XCD swizzle, grid (8, 64) = 512 wg
    int fid = (int)blockIdx.y * 8 + (int)blockIdx.x;
    int swz = (fid & 7) * 64 + (fid >> 3);
    const long bn = swz & 7, bm = swz >> 3;

    f32x4 acc[8][4] = {};
    pipe256(A + bm * 256 * 1024, Bcat + bn * 256 * 1024, lds, acc, tid);

    const long rbase = bm * 256 + wm * 128;
    const int chbase = (int)bn * 128 + wn * 32;
#pragma unroll
    for (int t = 0; t < 2; ++t) {
        int ch = chbase + t * 16 + (lane & 15);
        float g0 = gb[ch], i0 = ib[ch];
#pragma unroll
        for (int m = 0; m < 8; ++m) {
            long row = rbase + m * 16 + ((lane >> 4) << 2);
#pragma unroll
            for (int i = 0; i < 4; ++i) {
                float pg = acc[m][2 * t][i] + g0;
                float pi = acc[m][2 * t + 1][i] + i0;
                float aa = 1.0f / (1.0f + __expf(-pg));
                float bb = (1.0f - aa) * pi;
                ab[(row + i) * 1024 + ch] = (u32)f2bf(aa) | ((u32)f2bf(bb) << 16);
            }
        }
    }
}

// -------- final GEMM: out = h @ out_w + x + out_b (x residual as bf16) ------

__global__ __launch_bounds__(512, 1) void k_gemm_out8(
    const u16* __restrict__ A, const u16* __restrict__ Bt,
    const u16* __restrict__ xbf, const float* __restrict__ ob,
    float* __restrict__ out) {
    __shared__ __align__(16) u16 lds[65536];
    const int tid = threadIdx.x, lane = tid & 63;
    const int wm = (tid >> 6) >> 2, wn = (tid >> 6) & 3;

    // bijective XCD swizzle, grid (4, 64) = 256 wg
    int fid = (int)blockIdx.y * 4 + (int)blockIdx.x;
    int swz = (fid & 7) * 32 + (fid >> 3);
    const long bn = swz & 3, bm = swz >> 2;

    f32x4 acc[8][4] = {};
    pipe256(A + bm * 256 * 1024, Bt + bn * 256 * 1024, lds, acc, tid);

    const long rbase = bm * 256 + wm * 128;
    const int cbase = (int)bn * 256 + wn * 64;
#pragma unroll
    for (int n = 0; n < 4; ++n) {
        int col = cbase + n * 16 + (lane & 15);
        float o0 = ob[col];
#pragma unroll
        for (int m = 0; m < 8; ++m) {
            long row = rbase + m * 16 + ((lane >> 4) << 2);
#pragma unroll
            for (int i = 0; i < 4; ++i) {
                long o = (row + i) * 1024 + col;
                out[o] = acc[m][n][i] + o0 + bf2f(xbf[o]);
            }
        }
    }
}

// ---------------- conversions ----------------

__global__ __launch_bounds__(256) void k_cvt_x(const float4* __restrict__ x,
                                               uint2* __restrict__ o, int n4) {
    int i = blockIdx.x * 256 + threadIdx.x;
    if (i < n4) {
        float4 v = x[i];
        uint2 r;
        r.x = (u32)f2bf(v.x) | ((u32)f2bf(v.y) << 16);
        r.y = (u32)f2bf(v.z) | ((u32)f2bf(v.w) << 16);
        o[i] = r;
    }
}

__global__ __launch_bounds__(256) void k_transpose_bf(const float* __restrict__ w,
                                                      u16* __restrict__ wt, int R, int C) {
    __shared__ float t[32][33];
    int c0 = blockIdx.x * 32, r0 = blockIdx.y * 32;
    int x = threadIdx.x & 31, y = threadIdx.x >> 5;
    for (int i = y; i < 32; i += 8) t[i][x] = w[(size_t)(r0 + i) * C + c0 + x];
    __syncthreads();
    for (int i = y; i < 32; i += 8) wt[(size_t)(c0 + i) * R + r0 + x] = f2bf(t[x][i]);
}

// Interleaved concat transpose: rows 32t..32t+15 = gate ch 16t..16t+15,
// rows 32t+16..32t+31 = inp, same channels.
__global__ __launch_bounds__(256) void k_transpose_cat(const float* __restrict__ gw,
                                                       const float* __restrict__ iw,
                                                       u16* __restrict__ wt, int K, int C) {
    __shared__ float t[32][33];
    int c0 = blockIdx.x * 32, r0 = blockIdx.y * 32;
    const float* w = blockIdx.z ? iw : gw;
    int x = threadIdx.x & 31, y = threadIdx.x >> 5;
    for (int i = y; i < 32; i += 8) t[i][x] = w[(size_t)(r0 + i) * C + c0 + x];
    __syncthreads();
    for (int i = y; i < 32; i += 8) {
        int ch = c0 + i;
        int r = ((ch >> 4) << 5) | ((int)blockIdx.z << 4) | (ch & 15);
        wt[(size_t)r * K + r0 + x] = f2bf(t[x][i]);
    }
}

// ---------------- chunked affine scan (packed ab stream) ----------------
// ab[row*1024 + ch]: lo = a (bf16), hi = b (bf16). h_t = a*h + b over s.

__global__ __launch_bounds__(256) void k_scanA(const u32* __restrict__ ab,
                                               float2* __restrict__ cAB) {
    int e = blockIdx.x * 256 + threadIdx.x;  // 0..1023
    int c = blockIdx.y, bt = blockIdx.z;
    long base = ((long)bt * 4096 + c * 64) * 1024 + e;
    float Aa = 1.f, H = 0.f;
#pragma unroll 4
    for (int i = 0; i < 64; ++i) {
        u32 v = ab[base + (long)i * 1024];
        float a = bf2f((u16)v), b = bf2f((u16)(v >> 16));
        H = a * H + b;
        Aa *= a;
    }
    cAB[((long)bt * 64 + c) * 1024 + e] = make_float2(Aa, H);
}

__global__ __launch_bounds__(256) void k_scanB(const float2* __restrict__ cAB,
                                               float* __restrict__ hin) {
    int e = blockIdx.x * 256 + threadIdx.x;
    int bt = blockIdx.y;
    float H = 0.f;
#pragma unroll
    for (int c = 0; c < 64; ++c) {
        long s = ((long)bt * 64 + c) * 1024 + e;
        hin[s] = H;
        float2 v = cAB[s];
        H = v.x * H + v.y;
    }
}

__global__ __launch_bounds__(256) void k_scanC(const u32* __restrict__ ab,
                                               const float* __restrict__ hin,
                                               u16* __restrict__ hout) {
    int e = blockIdx.x * 256 + threadIdx.x;
    int c = blockIdx.y, bt = blockIdx.z;
    long base = ((long)bt * 4096 + c * 64) * 1024 + e;
    float H = hin[((long)bt * 64 + c) * 1024 + e];
#pragma unroll 4
    for (int i = 0; i < 64; ++i) {
        u32 v = ab[base + (long)i * 1024];
        H = bf2f((u16)v) * H + bf2f((u16)(v >> 16));
        hout[base + (long)i * 1024] = f2bf(H);
    }
}

// ---------------- launch ----------------

extern "C" void kernel_launch(void* const* d_in, const int* in_sizes, int n_in,
                              void* d_out, int out_size, void* d_ws, size_t ws_size,
                              hipStream_t stream) {
    const float* x      = (const float*)d_in[0];
    const float* gate_w = (const float*)d_in[1];
    const float* gate_b = (const float*)d_in[2];
    const float* inp_w  = (const float*)d_in[3];
    const float* inp_b  = (const float*)d_in[4];
    const float* out_w  = (const float*)d_in[5];
    const float* out_b  = (const float*)d_in[6];
    float* out = (float*)d_out;

    const int Bsz = 4, S = 4096, Din = 1024, Dst = 1024;
    const int M = Bsz * S;                 // 16384
    const long nx = (long)M * Din;         // 16777216

    // workspace layout (bytes)
    char* w = (char*)d_ws;
    u16* xb      = (u16*)(w);                // 33,554,432  x bf16
    u16* catW    = (u16*)(w + 33554432);     //  4,194,304  [gate;inp] interleaved ^T
    u16* owT     = (u16*)(w + 37748736);     //  2,097,152  out_w^T bf16
    u16* hbf     = (u16*)(w + 39845888);     // 33,554,432  scan_out bf16
    float2* cAB  = (float2*)(w + 73400320);  //  2,097,152  chunk (A,H) pairs
    float* hin   = (float*)(w + 75497472);   //  1,048,576  chunk incoming states
    // total 76,546,048 B

    // packed ab lives in d_out (67,108,864 B); overwritten by final GEMM.
    u32* ab = (u32*)d_out;

    // 1. conversions
    k_cvt_x<<<(int)(nx / 4 / 256), 256, 0, stream>>>((const float4*)x, (uint2*)xb, (int)(nx / 4));
    k_transpose_cat<<<dim3(Dst / 32, Din / 32, 2), 256, 0, stream>>>(gate_w, inp_w, catW, Din, Dst);
    k_transpose_bf<<<dim3(Din / 32, Dst / 32), 256, 0, stream>>>(out_w, owT, Dst, Din);

    // 2. fused concat GEMM -> packed ab
    k_gemm_cat8<<<dim3(8, M / 256), 512, 0, stream>>>(xb, catW, gate_b, inp_b, ab);

    // 3. chunked scan -> h (bf16)
    k_scanA<<<dim3(4, 64, Bsz), 256, 0, stream>>>(ab, cAB);
    k_scanB<<<dim3(4, Bsz), 256, 0, stream>>>(cAB, hin);
    k_scanC<<<dim3(4, 64, Bsz), 256, 0, stream>>>(ab, hin, hbf);

    // 4. final GEMM: out = h @ out_w + x + out_b
    k_gemm_out8<<<dim3(4, M / 256), 512, 0, stream>>>(hbf, owT, xb, out_b, out);
}

// Round 13
// 175.802 us; speedup vs baseline: 1.7655x; 1.0834x over previous
//
#include <hip/hip_runtime.h>

typedef unsigned short u16;
typedef unsigned int   u32;
typedef __bf16 bf16x8 __attribute__((ext_vector_type(8)));
typedef float  f32x4  __attribute__((ext_vector_type(4)));

#define DEVI __device__ __forceinline__

DEVI u16 f2bf(float f) {
    union { float f; u32 u; } c; c.f = f;
    u32 u = c.u;
    u32 r = (u + 0x7fffu + ((u >> 16) & 1u)) >> 16;
    return (u16)r;
}
DEVI float bf2f(u16 v) {
    union { u32 u; float f; } c; c.u = ((u32)v) << 16;
    return c.f;
}

DEVI void gload16(const void* g, void* l) {
    __builtin_amdgcn_global_load_lds(
        (const __attribute__((address_space(1))) void*)g,
        (__attribute__((address_space(3))) void*)l, 16, 0, 0);
}

// ---------------- 256x256 8-phase GEMM (frozen from r12) ----------------
// LDS 128KB: buffer q at q*32768 (u16). Halves (16KB, [128 rows][64 K] bf16):
// A0 @+0, A1 @+8192, B0 @+16384, B1 @+24576. st_16x32 swizzle:
// u16 off(r,k) = r*64 + (k ^ (((r>>2)&1)<<4)); DMA dest linear, global
// source column pre-swizzled (rule 21). vmcnt gates before closing barriers
// (vmcnt per-wave; barrier globalizes — round-3 lesson).

#define VMW(N)  asm volatile("s_waitcnt vmcnt(" #N ")" ::: "memory")
#define LGKM(N) asm volatile("s_waitcnt lgkmcnt(" #N ")" ::: "memory")
#define BAR     __builtin_amdgcn_s_barrier()
#define SP1     __builtin_amdgcn_s_setprio(1)
#define SP0     __builtin_amdgcn_s_setprio(0)
#define SCB     __builtin_amdgcn_sched_barrier(0)

DEVI void stage_half(const u16* g, u16* slot, int tid) {
    const int r = tid >> 3;                                  // 0..63
    const int ks = ((tid & 7) << 3) ^ (((tid >> 5) & 1) << 4);
    gload16(g + (long)r * 1024 + ks, slot + tid * 8);
    gload16(g + (long)(r + 64) * 1024 + ks, slot + 4096 + tid * 8);
}

DEVI f32x4 mfma(const bf16x8& a, const bf16x8& b, const f32x4& c) {
    return __builtin_amdgcn_mfma_f32_16x16x32_bf16(a, b, c, 0, 0, 0);
}

#define PH(Q, M2, READB, STG, GATE)                                          \
    {                                                                        \
        if (READB) {                                                         \
            _Pragma("unroll")                                                \
            for (int n = 0; n < 4; ++n) {                                    \
                bh[n][0] = *(const bf16x8*)(lds + (Q) + bbase + n * 1024);   \
                bh[n][1] = *(const bf16x8*)(lds + (Q) + bbase + n * 1024 + 32); \
            }                                                                \
        }                                                                    \
        a0k0 = *(const bf16x8*)(lds + (Q) + abase + (M2) * 2048);            \
        a0k1 = *(const bf16x8*)(lds + (Q) + abase + (M2) * 2048 + 32);       \
        a1k0 = *(const bf16x8*)(lds + (Q) + abase + (M2) * 2048 + 1024);     \
        a1k1 = *(const bf16x8*)(lds + (Q) + abase + (M2) * 2048 + 1056);     \
        STG;                                                                 \
        if (READB) { LGKM(8); }                                              \
        BAR;                                                                 \
        LGKM(0); SCB;                                                        \
        SP1;                                                                 \
        _Pragma("unroll")                                                    \
        for (int n = 0; n < 4; ++n) {                                        \
            acc[(M2) * 2][n]     = mfma(a0k0, bh[n][0], acc[(M2) * 2][n]);   \
            acc[(M2) * 2][n]     = mfma(a0k1, bh[n][1], acc[(M2) * 2][n]);   \
            acc[(M2) * 2 + 1][n] = mfma(a1k0, bh[n][0], acc[(M2) * 2 + 1][n]); \
            acc[(M2) * 2 + 1][n] = mfma(a1k1, bh[n][1], acc[(M2) * 2 + 1][n]); \
        }                                                                    \
        SP0;                                                                 \
        GATE;                                                                \
        BAR;                                                                 \
    }

#define NOP do {} while (0)
#define AH(t, h) (Ab + (long)(h) * 131072 + (t) * 64)
#define BH(t, h) (Bb + (long)(h) * 131072 + (t) * 64)

DEVI void pipe256(const u16* Ab, const u16* Bb, u16* lds,
                  f32x4 (&acc)[8][4], int tid) {
    const int lane = tid & 63;
    const int wm = (tid >> 6) >> 2, wn = (tid >> 6) & 3;
    const int kswz = ((lane >> 4) << 3) ^ (((lane >> 2) & 1) << 4);
    const int abase = wm * 8192 + (lane & 15) * 64 + kswz;
    const int bbase = 16384 + (wn >> 1) * 8192 + ((wn & 1) * 64 + (lane & 15)) * 64 + kswz;

    stage_half(AH(0, 0), lds + 0,             tid);
    stage_half(AH(0, 1), lds + 8192,          tid);
    stage_half(BH(0, 0), lds + 16384,         tid);
    stage_half(BH(0, 1), lds + 24576,         tid);
    stage_half(BH(1, 0), lds + 32768 + 16384, tid);
    stage_half(BH(1, 1), lds + 32768 + 24576, tid);
    VMW(4); BAR;

    bf16x8 bh[4][2];
    bf16x8 a0k0, a0k1, a1k0, a1k1;

#pragma unroll 1
    for (int j = 0; j < 7; ++j) {
        const int T = 2 * j;
        PH(0, 0, 1, stage_half(AH(T + 1, 0), lds + 32768, tid), NOP);
        PH(0, 1, 0, stage_half(AH(T + 1, 1), lds + 32768 + 8192, tid), NOP);
        PH(0, 2, 0, stage_half(BH(T + 2, 0), lds + 16384, tid), NOP);
        PH(0, 3, 0, stage_half(BH(T + 2, 1), lds + 24576, tid), VMW(4));
        PH(32768, 0, 1, stage_half(AH(T + 2, 0), lds + 0, tid), NOP);
        PH(32768, 1, 0, stage_half(AH(T + 2, 1), lds + 8192, tid), NOP);
        PH(32768, 2, 0, stage_half(BH(T + 3, 0), lds + 32768 + 16384, tid), NOP);
        PH(32768, 3, 0, stage_half(BH(T + 3, 1), lds + 32768 + 24576, tid), VMW(4));
    }
    PH(0, 0, 1, stage_half(AH(15, 0), lds + 32768, tid), NOP);
    PH(0, 1, 0, stage_half(AH(15, 1), lds + 32768 + 8192, tid), NOP);
    PH(0, 2, 0, NOP, NOP);
    PH(0, 3, 0, NOP, VMW(0));
    PH(32768, 0, 1, NOP, NOP);
    PH(32768, 1, 0, NOP, NOP);
    PH(32768, 2, 0, NOP, NOP);
    PH(32768, 3, 0, NOP, NOP);
}

// ------- gate GEMM + fused sigmoid-gate + fused per-chunk scan (scanA) ------
// writes packed ab[row*1024 + ch] = bf16(a) | bf16(b)<<16, and per-chunk
// (A,B) composition to cAB[gc*1024 + ch] (gc = global_row/64).
// Wave wm covers rows [bm*256 + wm*128, +128) = 2 chunks of 64 rows.
// Composition uses the ROUNDED bf16 a,b (bit-consistent with scanC replay).

__global__ __launch_bounds__(512, 1) void k_gemm_cat8(
    const u16* __restrict__ A, const u16* __restrict__ Bcat,
    const float* __restrict__ gb, const float* __restrict__ ib,
    u32* __restrict__ ab, float2* __restrict__ cAB) {
    __shared__ __align__(16) u16 lds[65536];
    const int tid = threadIdx.x, lane = tid & 63;
    const int wm = (tid >> 6) >> 2, wn = (tid >> 6) & 3;

    // bijective XCD swizzle, grid (8, 64) = 512 wg
    int fid = (int)blockIdx.y * 8 + (int)blockIdx.x;
    int swz = (fid & 7) * 64 + (fid >> 3);
    const long bn = swz & 7, bm = swz >> 3;

    f32x4 acc[8][4] = {};
    pipe256(A + bm * 256 * 1024, Bcat + bn * 256 * 1024, lds, acc, tid);

    const long rbase = bm * 256 + wm * 128;
    const int chbase = (int)bn * 128 + wn * 32;
    float sA[2][8], sB[2][8];           // per-(t, m) 4-row segment (A,B)
#pragma unroll
    for (int t = 0; t < 2; ++t) {
        int ch = chbase + t * 16 + (lane & 15);
        float g0 = gb[ch], i0 = ib[ch];
#pragma unroll
        for (int m = 0; m < 8; ++m) {
            long row = rbase + m * 16 + ((lane >> 4) << 2);
            float Aseg = 1.0f, Bseg = 0.0f;
#pragma unroll
            for (int i = 0; i < 4; ++i) {
                float pg = acc[m][2 * t][i] + g0;
                float pi = acc[m][2 * t + 1][i] + i0;
                float aa = 1.0f / (1.0f + __expf(-pg));
                float bb = (1.0f - aa) * pi;
                u16 au = f2bf(aa), bu = f2bf(bb);
                ab[(row + i) * 1024 + ch] = (u32)au | ((u32)bu << 16);
                float ar = bf2f(au), br = bf2f(bu);
                Aseg = ar * Aseg;
                Bseg = ar * Bseg + br;
            }
            sA[t][m] = Aseg;
            sB[t][m] = Bseg;
        }
    }
    // compose across q-lanes (rows +4 apart) and m-groups -> 2 chunks/wave
#pragma unroll
    for (int t = 0; t < 2; ++t) {
#pragma unroll
        for (int c2 = 0; c2 < 2; ++c2) {
            float Ac = 1.0f, Bc = 0.0f;
#pragma unroll
            for (int mm = 0; mm < 4; ++mm) {
                int m = c2 * 4 + mm;
#pragma unroll
                for (int q = 0; q < 4; ++q) {
                    float Aq = __shfl(sA[t][m], (lane & 15) + q * 16);
                    float Bq = __shfl(sB[t][m], (lane & 15) + q * 16);
                    Ac = Aq * Ac;
                    Bc = Aq * Bc + Bq;
                }
            }
            if ((lane >> 4) == 0) {
                long gc = (rbase >> 6) + c2;            // global chunk id
                int ch = chbase + t * 16 + (lane & 15);
                cAB[gc * 1024 + ch] = make_float2(Ac, Bc);
            }
        }
    }
}

// -------- final GEMM: out = h @ out_w + x + out_b (x residual as bf16) ------

__global__ __launch_bounds__(512, 1) void k_gemm_out8(
    const u16* __restrict__ A, const u16* __restrict__ Bt,
    const u16* __restrict__ xbf, const float* __restrict__ ob,
    float* __restrict__ out) {
    __shared__ __align__(16) u16 lds[65536];
    const int tid = threadIdx.x, lane = tid & 63;
    const int wm = (tid >> 6) >> 2, wn = (tid >> 6) & 3;

    // bijective XCD swizzle, grid (4, 64) = 256 wg
    int fid = (int)blockIdx.y * 4 + (int)blockIdx.x;
    int swz = (fid & 7) * 32 + (fid >> 3);
    const long bn = swz & 3, bm = swz >> 2;

    f32x4 acc[8][4] = {};
    pipe256(A + bm * 256 * 1024, Bt + bn * 256 * 1024, lds, acc, tid);

    const long rbase = bm * 256 + wm * 128;
    const int cbase = (int)bn * 256 + wn * 64;
#pragma unroll
    for (int n = 0; n < 4; ++n) {
        int col = cbase + n * 16 + (lane & 15);
        float o0 = ob[col];
#pragma unroll
        for (int m = 0; m < 8; ++m) {
            long row = rbase + m * 16 + ((lane >> 4) << 2);
#pragma unroll
            for (int i = 0; i < 4; ++i) {
                long o = (row + i) * 1024 + col;
                out[o] = acc[m][n][i] + o0 + bf2f(xbf[o]);
            }
        }
    }
}

// ------------- fused prep: cvt_x + transpose_cat + transpose_bf -------------
// flat grid: [0,16384) cvt x->bf16; [16384,18432) cat-transpose (32x32x2);
// [18432,19456) out_w transpose (32x32).

__global__ __launch_bounds__(256) void k_prep(
    const float4* __restrict__ x4, uint2* __restrict__ xb2,
    const float* __restrict__ gw, const float* __restrict__ iw,
    u16* __restrict__ catW, const float* __restrict__ ow,
    u16* __restrict__ owT) {
    __shared__ float t[32][33];
    int bid = blockIdx.x;
    if (bid < 16384) {
        int i = bid * 256 + threadIdx.x;     // < 16777216/4
        float4 v = x4[i];
        uint2 r;
        r.x = (u32)f2bf(v.x) | ((u32)f2bf(v.y) << 16);
        r.y = (u32)f2bf(v.z) | ((u32)f2bf(v.w) << 16);
        xb2[i] = r;
        return;
    }
    int xi = threadIdx.x & 31, y = threadIdx.x >> 5;
    if (bid < 18432) {
        int q = bid - 16384;
        int c0 = (q & 31) * 32, r0 = ((q >> 5) & 31) * 32, z = q >> 10;
        const float* w = z ? iw : gw;
        for (int i = y; i < 32; i += 8) t[i][xi] = w[(size_t)(r0 + i) * 1024 + c0 + xi];
        __syncthreads();
        for (int i = y; i < 32; i += 8) {
            int ch = c0 + i;
            int r = ((ch >> 4) << 5) | (z << 4) | (ch & 15);
            catW[(size_t)r * 1024 + r0 + xi] = f2bf(t[xi][i]);
        }
    } else {
        int q = bid - 18432;
        int c0 = (q & 31) * 32, r0 = (q >> 5) * 32;
        for (int i = y; i < 32; i += 8) t[i][xi] = ow[(size_t)(r0 + i) * 1024 + c0 + xi];
        __syncthreads();
        for (int i = y; i < 32; i += 8)
            owT[(size_t)(c0 + i) * 1024 + r0 + xi] = f2bf(t[xi][i]);
    }
}

// ---------------- chunked affine scan phases B & C ----------------

__global__ __launch_bounds__(256) void k_scanB(const float2* __restrict__ cAB,
                                               float* __restrict__ hin) {
    int e = blockIdx.x * 256 + threadIdx.x;
    int bt = blockIdx.y;
    float H = 0.f;
#pragma unroll
    for (int c = 0; c < 64; ++c) {
        long s = ((long)bt * 64 + c) * 1024 + e;
        hin[s] = H;
        float2 v = cAB[s];
        H = v.x * H + v.y;
    }
}

__global__ __launch_bounds__(256) void k_scanC(const u32* __restrict__ ab,
                                               const float* __restrict__ hin,
                                               u16* __restrict__ hout) {
    int e = blockIdx.x * 256 + threadIdx.x;
    int c = blockIdx.y, bt = blockIdx.z;
    long base = ((long)bt * 4096 + c * 64) * 1024 + e;
    float H = hin[((long)bt * 64 + c) * 1024 + e];
#pragma unroll 4
    for (int i = 0; i < 64; ++i) {
        u32 v = ab[base + (long)i * 1024];
        H = bf2f((u16)v) * H + bf2f((u16)(v >> 16));
        hout[base + (long)i * 1024] = f2bf(H);
    }
}

// ---------------- launch ----------------

extern "C" void kernel_launch(void* const* d_in, const int* in_sizes, int n_in,
                              void* d_out, int out_size, void* d_ws, size_t ws_size,
                              hipStream_t stream) {
    const float* x      = (const float*)d_in[0];
    const float* gate_w = (const float*)d_in[1];
    const float* gate_b = (const float*)d_in[2];
    const float* inp_w  = (const float*)d_in[3];
    const float* inp_b  = (const float*)d_in[4];
    const float* out_w  = (const float*)d_in[5];
    const float* out_b  = (const float*)d_in[6];
    float* out = (float*)d_out;

    const int Bsz = 4, S = 4096, Din = 1024, Dst = 1024;
    const int M = Bsz * S;                 // 16384

    // workspace layout (bytes)
    char* w = (char*)d_ws;
    u16* xb      = (u16*)(w);                // 33,554,432  x bf16
    u16* catW    = (u16*)(w + 33554432);     //  4,194,304  [gate;inp] interleaved ^T
    u16* owT     = (u16*)(w + 37748736);     //  2,097,152  out_w^T bf16
    u16* hbf     = (u16*)(w + 39845888);     // 33,554,432  scan_out bf16
    float2* cAB  = (float2*)(w + 73400320);  //  2,097,152  chunk (A,H) pairs
    float* hin   = (float*)(w + 75497472);   //  1,048,576  chunk incoming states
    // total 76,546,048 B

    // packed ab lives in d_out (67,108,864 B); overwritten by final GEMM.
    u32* ab = (u32*)d_out;

    // 1. fused prep (cvt + both transposes)
    k_prep<<<19456, 256, 0, stream>>>((const float4*)x, (uint2*)xb,
                                      gate_w, inp_w, catW, out_w, owT);

    // 2. fused concat GEMM -> packed ab + per-chunk scan composition
    k_gemm_cat8<<<dim3(8, M / 256), 512, 0, stream>>>(xb, catW, gate_b, inp_b, ab, cAB);

    // 3. scan combine + replay -> h (bf16)
    k_scanB<<<dim3(4, Bsz), 256, 0, stream>>>(cAB, hin);
    k_scanC<<<dim3(4, 64, Bsz), 256, 0, stream>>>(ab, hin, hbf);

    // 4. final GEMM: out = h @ out_w + x + out_b
    k_gemm_out8<<<dim3(4, M / 256), 512, 0, stream>>>(hbf, owT, xb, out_b, out);
}

// Round 14
// 175.240 us; speedup vs baseline: 1.7712x; 1.0032x over previous
//
#include <hip/hip_runtime.h>

typedef unsigned short u16;
typedef unsigned int   u32;
typedef __bf16 bf16x8 __attribute__((ext_vector_type(8)));
typedef float  f32x4  __attribute__((ext_vector_type(4)));

#define DEVI __device__ __forceinline__

DEVI u16 f2bf(float f) {
    union { float f; u32 u; } c; c.f = f;
    u32 u = c.u;
    u32 r = (u + 0x7fffu + ((u >> 16) & 1u)) >> 16;
    return (u16)r;
}
DEVI float bf2f(u16 v) {
    union { u32 u; float f; } c; c.u = ((u32)v) << 16;
    return c.f;
}

DEVI void gload16(const void* g, void* l) {
    __builtin_amdgcn_global_load_lds(
        (const __attribute__((address_space(1))) void*)g,
        (__attribute__((address_space(3))) void*)l, 16, 0, 0);
}

// ---------------- 256x256 GEMM, 2 phases per K-tile ----------------
// LDS 128KB: buffer q at q*32768 (u16). Halves (16KB, [128 rows][64 K] bf16):
// A0 @+0, A1 @+8192, B0 @+16384, B1 @+24576. st_16x32 swizzle:
// u16 off(r,k) = r*64 + (k ^ (((r>>2)&1)<<4)); DMA dest linear, global
// source column pre-swizzled (rule 21).
// Phase = {reads(bh if first + 4 A) ; stage ; BAR ; lgkm0+schedbar ; setprio1;
// 16 MFMA ; [4 more A-reads, compiler-waited] ; 16 MFMA ; setprio0 ; [gate];
// BAR} — 2 phases/tile, 4 barriers/tile (was 8), 32 MFMA per burst window.
// Ledger (per-wave vmcnt, gates BEFORE closing barrier — round-3 rule):
// stage A(T+1)x2 at T.phA, B(T+2)x2 at T.phB; gate VMW(4) at T.phB leaves
// exactly B(T+2)'s 4 loads in flight; every half lands >=1 gated barrier
// before its consuming phase. Prologue 6 halves + VMW(4); tail VMW(0).

#define VMW(N)  asm volatile("s_waitcnt vmcnt(" #N ")" ::: "memory")
#define LGKM0   asm volatile("s_waitcnt lgkmcnt(0)" ::: "memory")
#define BAR     __builtin_amdgcn_s_barrier()
#define SP1     __builtin_amdgcn_s_setprio(1)
#define SP0     __builtin_amdgcn_s_setprio(0)
#define SCB     __builtin_amdgcn_sched_barrier(0)

DEVI void stage_half(const u16* g, u16* slot, int tid) {
    const int r = tid >> 3;                                  // 0..63
    const int ks = ((tid & 7) << 3) ^ (((tid >> 5) & 1) << 4);
    gload16(g + (long)r * 1024 + ks, slot + tid * 8);
    gload16(g + (long)(r + 64) * 1024 + ks, slot + 4096 + tid * 8);
}

DEVI f32x4 mfma(const bf16x8& a, const bf16x8& b, const f32x4& c) {
    return __builtin_amdgcn_mfma_f32_16x16x32_bf16(a, b, c, 0, 0, 0);
}

// one merged phase: Q = buffer base, MB = first m-pair (0 or 2)
#define PH2(Q, MB, READB, STG, GATE)                                         \
    {                                                                        \
        if (READB) {                                                         \
            _Pragma("unroll")                                                \
            for (int n = 0; n < 4; ++n) {                                    \
                bh[n][0] = *(const bf16x8*)(lds + (Q) + bbase + n * 1024);   \
                bh[n][1] = *(const bf16x8*)(lds + (Q) + bbase + n * 1024 + 32); \
            }                                                                \
        }                                                                    \
        bf16x8 a0k0 = *(const bf16x8*)(lds + (Q) + abase + (MB) * 2048);     \
        bf16x8 a0k1 = *(const bf16x8*)(lds + (Q) + abase + (MB) * 2048 + 32); \
        bf16x8 a1k0 = *(const bf16x8*)(lds + (Q) + abase + (MB) * 2048 + 1024); \
        bf16x8 a1k1 = *(const bf16x8*)(lds + (Q) + abase + (MB) * 2048 + 1056); \
        STG;                                                                 \
        BAR;                                                                 \
        LGKM0; SCB;                                                          \
        SP1;                                                                 \
        _Pragma("unroll")                                                    \
        for (int n = 0; n < 4; ++n) {                                        \
            acc[(MB) * 2][n]     = mfma(a0k0, bh[n][0], acc[(MB) * 2][n]);   \
            acc[(MB) * 2][n]     = mfma(a0k1, bh[n][1], acc[(MB) * 2][n]);   \
            acc[(MB) * 2 + 1][n] = mfma(a1k0, bh[n][0], acc[(MB) * 2 + 1][n]); \
            acc[(MB) * 2 + 1][n] = mfma(a1k1, bh[n][1], acc[(MB) * 2 + 1][n]); \
        }                                                                    \
        {                                                                    \
            const int M2 = (MB) + 1;                                         \
            bf16x8 c0k0 = *(const bf16x8*)(lds + (Q) + abase + M2 * 2048);   \
            bf16x8 c0k1 = *(const bf16x8*)(lds + (Q) + abase + M2 * 2048 + 32); \
            bf16x8 c1k0 = *(const bf16x8*)(lds + (Q) + abase + M2 * 2048 + 1024); \
            bf16x8 c1k1 = *(const bf16x8*)(lds + (Q) + abase + M2 * 2048 + 1056); \
            _Pragma("unroll")                                                \
            for (int n = 0; n < 4; ++n) {                                    \
                acc[M2 * 2][n]     = mfma(c0k0, bh[n][0], acc[M2 * 2][n]);   \
                acc[M2 * 2][n]     = mfma(c0k1, bh[n][1], acc[M2 * 2][n]);   \
                acc[M2 * 2 + 1][n] = mfma(c1k0, bh[n][0], acc[M2 * 2 + 1][n]); \
                acc[M2 * 2 + 1][n] = mfma(c1k1, bh[n][1], acc[M2 * 2 + 1][n]); \
            }                                                                \
        }                                                                    \
        SP0;                                                                 \
        GATE;                                                                \
        BAR;                                                                 \
    }

#define NOP do {} while (0)
#define AH(t, h) (Ab + (long)(h) * 131072 + (t) * 64)
#define BH(t, h) (Bb + (long)(h) * 131072 + (t) * 64)

DEVI void pipe256(const u16* Ab, const u16* Bb, u16* lds,
                  f32x4 (&acc)[8][4], int tid) {
    const int lane = tid & 63;
    const int wm = (tid >> 6) >> 2, wn = (tid >> 6) & 3;
    const int kswz = ((lane >> 4) << 3) ^ (((lane >> 2) & 1) << 4);
    const int abase = wm * 8192 + (lane & 15) * 64 + kswz;
    const int bbase = 16384 + (wn >> 1) * 8192 + ((wn & 1) * 64 + (lane & 15)) * 64 + kswz;

    stage_half(AH(0, 0), lds + 0,             tid);
    stage_half(AH(0, 1), lds + 8192,          tid);
    stage_half(BH(0, 0), lds + 16384,         tid);
    stage_half(BH(0, 1), lds + 24576,         tid);
    stage_half(BH(1, 0), lds + 32768 + 16384, tid);
    stage_half(BH(1, 1), lds + 32768 + 24576, tid);
    VMW(4); BAR;                 // T0 landed; T1.B (4 loads) in flight

    bf16x8 bh[4][2];

#pragma unroll 1
    for (int j = 0; j < 7; ++j) {
        const int T = 2 * j;
        // tile T (buf0)
        PH2(0, 0, 1,
            { stage_half(AH(T + 1, 0), lds + 32768, tid);
              stage_half(AH(T + 1, 1), lds + 32768 + 8192, tid); }, NOP);
        PH2(0, 2, 0,
            { stage_half(BH(T + 2, 0), lds + 16384, tid);
              stage_half(BH(T + 2, 1), lds + 24576, tid); }, VMW(4));
        // tile T+1 (buf1)
        PH2(32768, 0, 1,
            { stage_half(AH(T + 2, 0), lds + 0, tid);
              stage_half(AH(T + 2, 1), lds + 8192, tid); }, NOP);
        PH2(32768, 2, 0,
            { stage_half(BH(T + 3, 0), lds + 32768 + 16384, tid);
              stage_half(BH(T + 3, 1), lds + 32768 + 24576, tid); }, VMW(4));
    }
    // tail: tile 14 (stages T15.A only, then full drain), tile 15 (none)
    PH2(0, 0, 1,
        { stage_half(AH(15, 0), lds + 32768, tid);
          stage_half(AH(15, 1), lds + 32768 + 8192, tid); }, NOP);
    PH2(0, 2, 0, NOP, VMW(0));
    PH2(32768, 0, 1, NOP, NOP);
    PH2(32768, 2, 0, NOP, NOP);
}

// ------- gate GEMM + fused sigmoid-gate + fused per-chunk scan (scanA) ------
// writes packed ab[row*1024 + ch] = bf16(a) | bf16(b)<<16, and per-chunk
// (A,B) composition to cAB[gc*1024 + ch] (gc = global_row/64), using the
// ROUNDED bf16 a,b (bit-consistent with scanC replay).

__global__ __launch_bounds__(512, 1) void k_gemm_cat8(
    const u16* __restrict__ A, const u16* __restrict__ Bcat,
    const float* __restrict__ gb, const float* __restrict__ ib,
    u32* __restrict__ ab, float2* __restrict__ cAB) {
    __shared__ __align__(16) u16 lds[65536];
    const int tid = threadIdx.x, lane = tid & 63;
    const int wm = (tid >> 6) >> 2, wn = (tid >> 6) & 3;

    // bijective XCD swizzle, grid (8, 64) = 512 wg
    int fid = (int)blockIdx.y * 8 + (int)blockIdx.x;
    int swz = (fid & 7) * 64 + (fid >> 3);
    const long bn = swz & 7, bm = swz >> 3;

    f32x4 acc[8][4] = {};
    pipe256(A + bm * 256 * 1024, Bcat + bn * 256 * 1024, lds, acc, tid);

    const long rbase = bm * 256 + wm * 128;
    const int chbase = (int)bn * 128 + wn * 32;
    float sA[2][8], sB[2][8];
#pragma unroll
    for (int t = 0; t < 2; ++t) {
        int ch = chbase + t * 16 + (lane & 15);
        float g0 = gb[ch], i0 = ib[ch];
#pragma unroll
        for (int m = 0; m < 8; ++m) {
            long row = rbase + m * 16 + ((lane >> 4) << 2);
            float Aseg = 1.0f, Bseg = 0.0f;
#pragma unroll
            for (int i = 0; i < 4; ++i) {
                float pg = acc[m][2 * t][i] + g0;
                float pi = acc[m][2 * t + 1][i] + i0;
                float aa = 1.0f / (1.0f + __expf(-pg));
                float bb = (1.0f - aa) * pi;
                u16 au = f2bf(aa), bu = f2bf(bb);
                ab[(row + i) * 1024 + ch] = (u32)au | ((u32)bu << 16);
                float ar = bf2f(au), br = bf2f(bu);
                Aseg = ar * Aseg;
                Bseg = ar * Bseg + br;
            }
            sA[t][m] = Aseg;
            sB[t][m] = Bseg;
        }
    }
#pragma unroll
    for (int t = 0; t < 2; ++t) {
#pragma unroll
        for (int c2 = 0; c2 < 2; ++c2) {
            float Ac = 1.0f, Bc = 0.0f;
#pragma unroll
            for (int mm = 0; mm < 4; ++mm) {
                int m = c2 * 4 + mm;
#pragma unroll
                for (int q = 0; q < 4; ++q) {
                    float Aq = __shfl(sA[t][m], (lane & 15) + q * 16);
                    float Bq = __shfl(sB[t][m], (lane & 15) + q * 16);
                    Ac = Aq * Ac;
                    Bc = Aq * Bc + Bq;
                }
            }
            if ((lane >> 4) == 0) {
                long gc = (rbase >> 6) + c2;
                int ch = chbase + t * 16 + (lane & 15);
                cAB[gc * 1024 + ch] = make_float2(Ac, Bc);
            }
        }
    }
}

// -------- final GEMM: out = h @ out_w + x + out_b (x residual as bf16) ------

__global__ __launch_bounds__(512, 1) void k_gemm_out8(
    const u16* __restrict__ A, const u16* __restrict__ Bt,
    const u16* __restrict__ xbf, const float* __restrict__ ob,
    float* __restrict__ out) {
    __shared__ __align__(16) u16 lds[65536];
    const int tid = threadIdx.x, lane = tid & 63;
    const int wm = (tid >> 6) >> 2, wn = (tid >> 6) & 3;

    // bijective XCD swizzle, grid (4, 64) = 256 wg
    int fid = (int)blockIdx.y * 4 + (int)blockIdx.x;
    int swz = (fid & 7) * 32 + (fid >> 3);
    const long bn = swz & 3, bm = swz >> 2;

    f32x4 acc[8][4] = {};
    pipe256(A + bm * 256 * 1024, Bt + bn * 256 * 1024, lds, acc, tid);

    const long rbase = bm * 256 + wm * 128;
    const int cbase = (int)bn * 256 + wn * 64;
#pragma unroll
    for (int n = 0; n < 4; ++n) {
        int col = cbase + n * 16 + (lane & 15);
        float o0 = ob[col];
#pragma unroll
        for (int m = 0; m < 8; ++m) {
            long row = rbase + m * 16 + ((lane >> 4) << 2);
#pragma unroll
            for (int i = 0; i < 4; ++i) {
                long o = (row + i) * 1024 + col;
                out[o] = acc[m][n][i] + o0 + bf2f(xbf[o]);
            }
        }
    }
}

// ------------- fused prep: cvt_x + transpose_cat + transpose_bf -------------

__global__ __launch_bounds__(256) void k_prep(
    const float4* __restrict__ x4, uint2* __restrict__ xb2,
    const float* __restrict__ gw, const float* __restrict__ iw,
    u16* __restrict__ catW, const float* __restrict__ ow,
    u16* __restrict__ owT) {
    __shared__ float t[32][33];
    int bid = blockIdx.x;
    if (bid < 16384) {
        int i = bid * 256 + threadIdx.x;
        float4 v = x4[i];
        uint2 r;
        r.x = (u32)f2bf(v.x) | ((u32)f2bf(v.y) << 16);
        r.y = (u32)f2bf(v.z) | ((u32)f2bf(v.w) << 16);
        xb2[i] = r;
        return;
    }
    int xi = threadIdx.x & 31, y = threadIdx.x >> 5;
    if (bid < 18432) {
        int q = bid - 16384;
        int c0 = (q & 31) * 32, r0 = ((q >> 5) & 31) * 32, z = q >> 10;
        const float* w = z ? iw : gw;
        for (int i = y; i < 32; i += 8) t[i][xi] = w[(size_t)(r0 + i) * 1024 + c0 + xi];
        __syncthreads();
        for (int i = y; i < 32; i += 8) {
            int ch = c0 + i;
            int r = ((ch >> 4) << 5) | (z << 4) | (ch & 15);
            catW[(size_t)r * 1024 + r0 + xi] = f2bf(t[xi][i]);
        }
    } else {
        int q = bid - 18432;
        int c0 = (q & 31) * 32, r0 = (q >> 5) * 32;
        for (int i = y; i < 32; i += 8) t[i][xi] = ow[(size_t)(r0 + i) * 1024 + c0 + xi];
        __syncthreads();
        for (int i = y; i < 32; i += 8)
            owT[(size_t)(c0 + i) * 1024 + r0 + xi] = f2bf(t[xi][i]);
    }
}

// ---------------- chunked affine scan phases B & C ----------------

__global__ __launch_bounds__(256) void k_scanB(const float2* __restrict__ cAB,
                                               float* __restrict__ hin) {
    int e = blockIdx.x * 256 + threadIdx.x;
    int bt = blockIdx.y;
    float H = 0.f;
#pragma unroll
    for (int c = 0; c < 64; ++c) {
        long s = ((long)bt * 64 + c) * 1024 + e;
        hin[s] = H;
        float2 v = cAB[s];
        H = v.x * H + v.y;
    }
}

__global__ __launch_bounds__(256) void k_scanC(const u32* __restrict__ ab,
                                               const float* __restrict__ hin,
                                               u16* __restrict__ hout) {
    int e = blockIdx.x * 256 + threadIdx.x;
    int c = blockIdx.y, bt = blockIdx.z;
    long base = ((long)bt * 4096 + c * 64) * 1024 + e;
    float H = hin[((long)bt * 64 + c) * 1024 + e];
#pragma unroll 4
    for (int i = 0; i < 64; ++i) {
        u32 v = ab[base + (long)i * 1024];
        H = bf2f((u16)v) * H + bf2f((u16)(v >> 16));
        hout[base + (long)i * 1024] = f2bf(H);
    }
}

// ---------------- launch ----------------

extern "C" void kernel_launch(void* const* d_in, const int* in_sizes, int n_in,
                              void* d_out, int out_size, void* d_ws, size_t ws_size,
                              hipStream_t stream) {
    const float* x      = (const float*)d_in[0];
    const float* gate_w = (const float*)d_in[1];
    const float* gate_b = (const float*)d_in[2];
    const float* inp_w  = (const float*)d_in[3];
    const float* inp_b  = (const float*)d_in[4];
    const float* out_w  = (const float*)d_in[5];
    const float* out_b  = (const float*)d_in[6];
    float* out = (float*)d_out;

    const int Bsz = 4, S = 4096, Din = 1024, Dst = 1024;
    const int M = Bsz * S;                 // 16384

    // workspace layout (bytes)
    char* w = (char*)d_ws;
    u16* xb      = (u16*)(w);                // 33,554,432  x bf16
    u16* catW    = (u16*)(w + 33554432);     //  4,194,304  [gate;inp] interleaved ^T
    u16* owT     = (u16*)(w + 37748736);     //  2,097,152  out_w^T bf16
    u16* hbf     = (u16*)(w + 39845888);     // 33,554,432  scan_out bf16
    float2* cAB  = (float2*)(w + 73400320);  //  2,097,152  chunk (A,H) pairs
    float* hin   = (float*)(w + 75497472);   //  1,048,576  chunk incoming states
    // total 76,546,048 B

    // packed ab lives in d_out (67,108,864 B); overwritten by final GEMM.
    u32* ab = (u32*)d_out;

    // 1. fused prep (cvt + both transposes)
    k_prep<<<19456, 256, 0, stream>>>((const float4*)x, (uint2*)xb,
                                      gate_w, inp_w, catW, out_w, owT);

    // 2. fused concat GEMM -> packed ab + per-chunk scan composition
    k_gemm_cat8<<<dim3(8, M / 256), 512, 0, stream>>>(xb, catW, gate_b, inp_b, ab, cAB);

    // 3. scan combine + replay -> h (bf16)
    k_scanB<<<dim3(4, Bsz), 256, 0, stream>>>(cAB, hin);
    k_scanC<<<dim3(4, 64, Bsz), 256, 0, stream>>>(ab, hin, hbf);

    // 4. final GEMM: out = h @ out_w + x + out_b
    k_gemm_out8<<<dim3(4, M / 256), 512, 0, stream>>>(hbf, owT, xb, out_b, out);
}